// Round 4
// baseline (1352.782 us; speedup 1.0000x reference)
//
#include <hip/hip_runtime.h>

// SparseGO: out[b][t] = sum_g x[b][g] * (weight[g][t] * mask[g][t])
// mask has 1..4 nonzeros (value 1.0) per gene row g. nnz_total <= 80000.
//
// Pipeline (~2.6 MB workspace):
//   1) zero_ws: clear cscP + counts (padding entries must read {w=0,g=0}).
//   2) build_csc: streaming nz-scan of mask, 8 float4 loads/thread/iter with
//      a manual software pipeline (issue next batch BEFORE processing the
//      current batch's rare nz slow-path). Keeps ~8KB/wave in flight across
//      the atomic stalls that serialized all previous variants (~510 GB/s).
//      Nontemporal mask loads keep x resident in L3 for row_spmm.
//      Nonzeros go to a pair-packed transposed CSC:
//      cscP[p][t] = float4{w0,g0,w1,g1} for entries k=2p,2p+1 of term t.
//   3) row_spmm: one block per batch row; x row (80 KB) staged in LDS once;
//      lanes = terms; pair-packed metadata (dwordx4 = 2 entries) with
//      depth-2 prefetch (4 loads in flight per thread).
// Fallback (tiny ws): previous verified scatter kernel.

#define BATCH  4096
#define GENES  20000
#define NTERMS 5000
#define MAXNZ  4
#define CAP    64     // per-term cap; counts ~Poisson(16), P(>=64) ~ 1e-19
#define RTHREADS 1024
#define SBLK   2048   // blocks for the streaming scan
#define SVEC   8      // float4 loads per thread per pipeline stage

typedef float vf4 __attribute__((ext_vector_type(4)));

// ---------------------------------------------------------------- fast path

// clear cscP (2.56 MB) + counts (20 KB) in one pass
__global__ __launch_bounds__(256) void zero_ws(float4* __restrict__ ws,
                                               int n16) {
  const int stride = gridDim.x * 256;
  for (int i = blockIdx.x * 256 + threadIdx.x; i < n16; i += stride)
    ws[i] = make_float4(0.f, 0.f, 0.f, 0.f);
}

// software-pipelined streaming nz-scan of mask -> pair-packed CSC
__global__ __launch_bounds__(256) void build_csc(
    const float* __restrict__ mask, const float* __restrict__ weight,
    float2* __restrict__ cscP, int* __restrict__ counts) {
  const int n4 = GENES * NTERMS / 4;            // 25,000,000 float4s
  const int tid0 = blockIdx.x * 256 + threadIdx.x;
  const int lstride = SBLK * 256;               // 524,288
  const int chunk = lstride * SVEC;             // 4,194,304
  const int niter = (n4 + chunk - 1) / chunk;   // 6
  const vf4* m4 = (const vf4*)mask;
  const vf4 z4 = {0.f, 0.f, 0.f, 0.f};

  vf4 cur[SVEC], nxt[SVEC];
#pragma unroll
  for (int k = 0; k < SVEC; ++k) {              // preload stage 0
    const int idx = tid0 + k * lstride;
    cur[k] = (idx < n4) ? __builtin_nontemporal_load(m4 + idx) : z4;
  }

  int base = 0;
  for (int it = 0; it < niter; ++it) {
    const int nbase = base + chunk;
#pragma unroll
    for (int k = 0; k < SVEC; ++k) {            // issue next stage's loads
      const int idx = nbase + tid0 + k * lstride;
      nxt[k] = (idx < n4) ? __builtin_nontemporal_load(m4 + idx) : z4;
    }
    // process current stage (rare slow path overlaps the loads above)
#pragma unroll
    for (int k = 0; k < SVEC; ++k) {
      const vf4 m = cur[k];
      if (m.x != 0.f || m.y != 0.f || m.z != 0.f || m.w != 0.f) {
        const int idx = base + tid0 + k * lstride;
        const float mv[4] = {m.x, m.y, m.z, m.w};
#pragma unroll
        for (int j = 0; j < 4; ++j) {
          if (mv[j] != 0.f) {
            const int e = idx * 4 + j;          // < 1e8, fits int
            const int g = e / NTERMS;           // magic-mul const division
            const int t = e - g * NTERMS;
            const float w = weight[e];
            const int pos = atomicAdd(&counts[t], 1);
            if (pos < CAP)
              cscP[(size_t)(pos >> 1) * (2 * NTERMS) + 2 * t + (pos & 1)] =
                  make_float2(w, __int_as_float(g));
          }
        }
      }
    }
#pragma unroll
    for (int k = 0; k < SVEC; ++k) cur[k] = nxt[k];
    base = nbase;
  }
}

// one block per batch row: x row in LDS, lanes over terms, pair-packed
// metadata with depth-2 prefetch (2 pairs = 4 entries in flight per stream).
__global__ __launch_bounds__(1024) void row_spmm(
    const float* __restrict__ x, const float4* __restrict__ cscP,
    const int* __restrict__ counts, float* __restrict__ out) {
  __shared__ __align__(16) float xrow[GENES];  // 80 KB -> 2 blocks/CU
  const int b = blockIdx.x;
  {
    const float4* xr4 = (const float4*)(x + (size_t)b * GENES);
    float4* s4 = (float4*)xrow;
    for (int i = threadIdx.x; i < GENES / 4; i += RTHREADS) s4[i] = xr4[i];
  }
  __syncthreads();

  const float4 z4 = make_float4(0.f, 0.f, 0.f, 0.f);
  float* orow = out + (size_t)b * NTERMS;
  for (int t0 = 0; t0 < NTERMS; t0 += 2 * RTHREADS) {
    const int t1 = t0 + threadIdx.x;
    const int t2 = t1 + RTHREADS;
    const bool v1 = t1 < NTERMS, v2 = t2 < NTERMS;
    const int np1 = v1 ? (min(counts[t1], CAP) + 1) >> 1 : 0;
    const int np2 = v2 ? (min(counts[t2], CAP) + 1) >> 1 : 0;
    const float4* q1 = cscP + (v1 ? t1 : 0);
    const float4* q2 = cscP + (v2 ? t2 : 0);
    float a1 = 0.f, a2 = 0.f;
    const int npm = max(np1, np2);
    // depth-2 prefetch; padded stages read {0,0,0,0} -> contribute 0*xrow[0]
    float4 f1 = (np1 > 0) ? q1[0] : z4;
    float4 g1 = (np1 > 1) ? q1[NTERMS] : z4;
    float4 f2 = (np2 > 0) ? q2[0] : z4;
    float4 g2 = (np2 > 1) ? q2[NTERMS] : z4;
    for (int p = 0; p < npm; p += 2) {
      const float4 c1 = f1, d1 = g1, c2 = f2, d2 = g2;
      f1 = (p + 2 < np1) ? q1[(size_t)(p + 2) * NTERMS] : z4;
      g1 = (p + 3 < np1) ? q1[(size_t)(p + 3) * NTERMS] : z4;
      f2 = (p + 2 < np2) ? q2[(size_t)(p + 2) * NTERMS] : z4;
      g2 = (p + 3 < np2) ? q2[(size_t)(p + 3) * NTERMS] : z4;
      a1 += c1.x * xrow[__float_as_int(c1.y)];
      a1 += c1.z * xrow[__float_as_int(c1.w)];
      a1 += d1.x * xrow[__float_as_int(d1.y)];
      a1 += d1.z * xrow[__float_as_int(d1.w)];
      a2 += c2.x * xrow[__float_as_int(c2.y)];
      a2 += c2.z * xrow[__float_as_int(c2.w)];
      a2 += d2.x * xrow[__float_as_int(d2.y)];
      a2 += d2.z * xrow[__float_as_int(d2.w)];
    }
    if (v1) orow[t1] = a1;
    if (v2) orow[t2] = a2;
  }
}

// ---------------------------------------------------------------- fallback

#define RROWS  2

__global__ __launch_bounds__(256) void build_table(
    const float* __restrict__ mask, const float* __restrict__ weight,
    int* __restrict__ terms, float* __restrict__ wvals) {
  const int g = blockIdx.x;
  __shared__ int cnt;
  if (threadIdx.x == 0) cnt = 0;
  __syncthreads();

  const float4* row = (const float4*)(mask + (size_t)g * NTERMS);
  const int n4 = NTERMS / 4;
  for (int i = threadIdx.x; i < n4; i += 256) {
    float4 m = row[i];
    if (m.x != 0.f || m.y != 0.f || m.z != 0.f || m.w != 0.f) {
      const float mv[4] = {m.x, m.y, m.z, m.w};
#pragma unroll
      for (int j = 0; j < 4; ++j) {
        if (mv[j] != 0.f) {
          int slot = atomicAdd(&cnt, 1);
          if (slot < MAXNZ) {
            int t = i * 4 + j;
            terms[g * MAXNZ + slot] = t;
            wvals[g * MAXNZ + slot] = weight[(size_t)g * NTERMS + t];
          }
        }
      }
    }
  }
  __syncthreads();
  if (threadIdx.x == 0) {
    int c = cnt < MAXNZ ? cnt : MAXNZ;
    for (int s = c; s < MAXNZ; ++s) {
      terms[g * MAXNZ + s] = 0;
      wvals[g * MAXNZ + s] = 0.f;
    }
  }
}

__global__ __launch_bounds__(256) void spmm_scatter(
    const float* __restrict__ x,
    const int* __restrict__ terms, const float* __restrict__ wvals,
    float* __restrict__ out) {
  __shared__ float acc[RROWS * NTERMS];
  for (int i = threadIdx.x; i < RROWS * NTERMS; i += 256) acc[i] = 0.f;
  __syncthreads();

  const int b0 = blockIdx.x * RROWS;
  for (int g = threadIdx.x; g < GENES; g += 256) {
    const int4  t4 = ((const int4*)terms)[g];
    const float4 w4 = ((const float4*)wvals)[g];
#pragma unroll
    for (int r = 0; r < RROWS; ++r) {
      const float xv = x[(size_t)(b0 + r) * GENES + g];
      float* a = acc + r * NTERMS;
      atomicAdd(&a[t4.x], xv * w4.x);
      atomicAdd(&a[t4.y], xv * w4.y);
      atomicAdd(&a[t4.z], xv * w4.z);
      atomicAdd(&a[t4.w], xv * w4.w);
    }
  }
  __syncthreads();

#pragma unroll
  for (int r = 0; r < RROWS; ++r) {
    const float* a = acc + r * NTERMS;
    float* o = out + (size_t)(b0 + r) * NTERMS;
    for (int t = threadIdx.x; t < NTERMS; t += 256) o[t] = a[t];
  }
}

// ---------------------------------------------------------------- launch

extern "C" void kernel_launch(void* const* d_in, const int* in_sizes, int n_in,
                              void* d_out, int out_size, void* d_ws, size_t ws_size,
                              hipStream_t stream) {
  const float* x      = (const float*)d_in[0];
  const float* weight = (const float*)d_in[1];
  const float* mask   = (const float*)d_in[2];
  float* out = (float*)d_out;

  const size_t csc_bytes    = (size_t)CAP * NTERMS * 8;   // 2,560,000 (16B-mult)
  const size_t counts_bytes = (size_t)NTERMS * 4;         //    20,000
  const size_t need = csc_bytes + counts_bytes;           // ~2.6 MB

  if (ws_size >= need) {
    float2* cscP   = (float2*)d_ws;
    int*    counts = (int*)((char*)d_ws + csc_bytes);
    const int n16 = (int)((csc_bytes + counts_bytes + 15) / 16);

    zero_ws<<<640, 256, 0, stream>>>((float4*)d_ws, n16);
    build_csc<<<SBLK, 256, 0, stream>>>(mask, weight, cscP, counts);
    row_spmm<<<BATCH, RTHREADS, 0, stream>>>(x, (const float4*)cscP, counts, out);
  } else {
    int*   terms = (int*)d_ws;
    float* wvals = (float*)((char*)d_ws + (size_t)GENES * MAXNZ * 4);

    build_table<<<GENES, 256, 0, stream>>>(mask, weight, terms, wvals);
    spmm_scatter<<<BATCH / RROWS, 256, 0, stream>>>(x, terms, wvals, out);
  }
}